// Round 3
// baseline (175.392 us; speedup 1.0000x reference)
//
#include <hip/hip_runtime.h>
#include <stdint.h>

#define DMAX 80
#define RPB  8      // rows per block (stride-4 within an alignment class)
#define BLK  256

typedef float f32x4 __attribute__((ext_vector_type(4)));

// ---------------------------------------------------------------------------
// Setup kernel:
//  - thread 0: detect mask dtype (bool8 / int32 / float32) using known m,
//    compact selected indices into idx_out[0..m).
//  - grid-stride over pair ranks p in [0,P), P = m(m+1)/2:
//      pairtab[p] = i | j<<8
//      coltab[c]  = p | k<<16  where column c = pp[p] * xsel[k]
//        [0,m)      order-1: p = P (sentinel pp=1), k = c
//        [m, m+P)   order-2: p = rank,              k = m (sentinel x=1)
//        [m+P, T)   order-3: run over k in [j, m) for each pair (i,j)
// ---------------------------------------------------------------------------
__global__ void maskde_setup(const void* __restrict__ mask_raw, int m,
                             int* __restrict__ idx_out,
                             uint32_t* __restrict__ pairtab,
                             uint32_t* __restrict__ coltab, int P) {
    int tid = blockIdx.x * blockDim.x + threadIdx.x;
    if (tid == 0) {
        const uint8_t* b8  = (const uint8_t*)mask_raw;
        const int*     b32 = (const int*)mask_raw;
        const float*   bf  = (const float*)mask_raw;
        int cnt = 0; bool ok = true;
        for (int i = 0; i < DMAX; ++i) { uint8_t v = b8[i]; if (v > 1) ok = false; cnt += (v != 0); }
        int mode;
        if (ok && cnt == m) {
            mode = 0;
        } else {
            cnt = 0; ok = true;
            for (int i = 0; i < DMAX; ++i) { int v = b32[i]; if (v != 0 && v != 1) ok = false; cnt += (v != 0); }
            mode = (ok && cnt == m) ? 1 : 2;
        }
        int k = 0;
        for (int i = 0; i < DMAX && k < m; ++i) {
            bool on = (mode == 0) ? (b8[i] != 0)
                    : (mode == 1) ? (b32[i] != 0)
                                  : (bf[i] != 0.0f);
            if (on) idx_out[k++] = i;
        }
    }

    int stride = gridDim.x * blockDim.x;
    for (int p = tid; p < P; p += stride) {
        int rem = p, i = 0;
        while (rem >= m - i) { rem -= (m - i); ++i; }
        int j = i + rem;

        pairtab[p] = (uint32_t)i | ((uint32_t)j << 8);

        if (p < m)
            coltab[p] = (uint32_t)P | ((uint32_t)p << 16);      // order-1
        coltab[m + p] = (uint32_t)p | ((uint32_t)m << 16);      // order-2

        // order-3 run for pair (i,j)
        int mi = m - i;
        long long Si  = ((long long)m * (m + 1) * (m + 2)
                       - (long long)mi * (mi + 1) * (mi + 2)) / 6;
        int Rij = ((m - i) + (m - j + 1)) * (j - i) / 2;
        uint32_t* t3 = coltab + m + P + Si + Rij;
        for (int k3 = j; k3 < m; ++k3)
            t3[k3 - j] = (uint32_t)p | ((uint32_t)k3 << 16);
    }
}

// ---------------------------------------------------------------------------
// Main kernel: block handles RPB rows, all congruent mod 4 (same 16B
// alignment class).  LDS: xls[RPB][m+1] selected values (+sentinel 1.0),
// pps[RPB][P+1] pair products (+sentinel 1.0).  Each output element is
// pps[p] * xls[k]: 2 LDS reads + 1 mul.  Table decode shared across rows.
// ---------------------------------------------------------------------------
__global__ __launch_bounds__(BLK) void
maskde_expand(const float* __restrict__ x, const int* __restrict__ idx,
              const uint32_t* __restrict__ pairtab,
              const uint32_t* __restrict__ coltab,
              float* __restrict__ out,
              int m, int T, int P, int rows) {
    extern __shared__ float smem[];
    const int XSTR  = m + 1;
    const int PPSTR = P + 1;
    float* xls = smem;               // RPB * XSTR
    float* pps = smem + RPB * XSTR;  // RPB * PPSTR

    const int cls  = blockIdx.x & 3;        // row mod 4 (alignment class)
    const int bi   = blockIdx.x >> 2;
    const int row0 = cls + 4 * (bi * RPB);  // r-th row = row0 + 4*r
    const int tid  = threadIdx.x;

    // phase 0: gather selected x values for all rows
    for (int q = tid; q < RPB * XSTR; q += BLK) {
        int r = q / XSTR, k = q - r * XSTR;
        int rr = row0 + 4 * r;
        float v = 1.0f;
        if (k < m && rr < rows) v = x[rr * DMAX + idx[k]];
        xls[q] = v;
    }
    __syncthreads();

    // phase 1: pair products per row
    for (int r = 0; r < RPB; ++r) {
        const float* xr = xls + r * XSTR;
        float*       pr = pps + r * PPSTR;
        for (int p = tid; p <= P; p += BLK) {
            float v = 1.0f;
            if (p < P) {
                uint32_t ij = pairtab[p];
                v = xr[ij & 0xFF] * xr[(ij >> 8) & 0xFF];
            }
            pr[p] = v;
        }
    }
    __syncthreads();

    // per-row output bases (all share alignment class)
    float* ob[RPB];
#pragma unroll
    for (int r = 0; r < RPB; ++r)
        ob[r] = out + (size_t)(row0 + 4 * r) * (size_t)T;

    uintptr_t a0 = (uintptr_t)ob[0];
    int k0 = (int)(((16 - (a0 & 15)) & 15) >> 2);
    if (k0 > T) k0 = T;
    const int nv     = (T - k0) >> 2;
    const int tstart = k0 + 4 * nv;
    const int tcnt   = T - tstart;
    const int scnt   = k0 + tcnt;

    // scalar prologue + tail for all rows
    if (scnt > 0) {
        for (int q = tid; q < RPB * scnt; q += BLK) {
            int r = q / scnt, w = q - r * scnt;
            int c = (w < k0) ? w : (tstart + (w - k0));
            int rr = row0 + 4 * r;
            if (rr < rows) {
                uint32_t e = coltab[c];
                ob[r][c] = pps[r * PPSTR + (int)(e & 0xFFFFu)]
                         * xls[r * XSTR  + (int)(e >> 16)];
            }
        }
    }

    // vector main loop: decode once, apply to RPB rows
    for (int v = tid; v < nv; v += BLK) {
        const uint32_t* tb = coltab + k0 + 4 * v;
        uint32_t e0 = tb[0], e1 = tb[1], e2 = tb[2], e3 = tb[3];
        int p0 = e0 & 0xFFFF, q0 = e0 >> 16;
        int p1 = e1 & 0xFFFF, q1 = e1 >> 16;
        int p2 = e2 & 0xFFFF, q2 = e2 >> 16;
        int p3 = e3 & 0xFFFF, q3 = e3 >> 16;
#pragma unroll
        for (int r = 0; r < RPB; ++r) {
            int rr = row0 + 4 * r;
            if (rr < rows) {
                const float* xr = xls + r * XSTR;
                const float* pr = pps + r * PPSTR;
                f32x4 o;
                o.x = pr[p0] * xr[q0];
                o.y = pr[p1] * xr[q1];
                o.z = pr[p2] * xr[q2];
                o.w = pr[p3] * xr[q3];
                __builtin_nontemporal_store(o, (f32x4*)(ob[r] + k0 + 4 * v));
            }
        }
    }
}

extern "C" void kernel_launch(void* const* d_in, const int* in_sizes, int n_in,
                              void* d_out, int out_size, void* d_ws, size_t ws_size,
                              hipStream_t stream) {
    const float* x    = (const float*)d_in[0];
    const void*  mask = d_in[1];
    float*       out  = (float*)d_out;

    int rows = in_sizes[0] / DMAX;
    if (rows <= 0 || out_size <= 0) return;
    long long T = (long long)out_size / rows;

    // recover m from T(m) = m + m(m+1)/2 + m(m+1)(m+2)/6
    int m = -1;
    for (int mm = 0; mm <= DMAX; ++mm) {
        long long t = (long long)mm
                    + (long long)mm * (mm + 1) / 2
                    + (long long)mm * (mm + 1) * (mm + 2) / 6;
        if (t == T) { m = mm; break; }
    }
    if (m <= 0) return;

    int P = m * (m + 1) / 2;

    int*      idx     = (int*)d_ws;
    uint32_t* pairtab = (uint32_t*)d_ws + 128;
    uint32_t* coltab  = pairtab + ((P + 31) & ~31);

    int sblocks = (P + 255) / 256;
    if (sblocks < 1) sblocks = 1;
    maskde_setup<<<sblocks, 256, 0, stream>>>(mask, m, idx, pairtab, coltab, P);

    int rpc    = (rows + 3) / 4;              // rows per alignment class
    int bpc    = (rpc + RPB - 1) / RPB;       // blocks per class
    int blocks = 4 * bpc;
    size_t shmem = (size_t)(RPB * (m + 1) + RPB * (P + 1)) * sizeof(float);
    maskde_expand<<<blocks, BLK, shmem, stream>>>(x, idx, pairtab, coltab, out,
                                                  m, (int)T, P, rows);
}

// Round 4
// 135.063 us; speedup vs baseline: 1.2986x; 1.2986x over previous
//
#include <hip/hip_runtime.h>
#include <stdint.h>

#define DMAX 80
#define BLK  256

typedef float f32x4 __attribute__((ext_vector_type(4)));

// ---------------------------------------------------------------------------
// Setup kernel:
//  - thread 0: detect mask dtype (bool8 / int32 / float32) using known m,
//    compact selected indices into idx_out[0..m).
//  - grid-stride over pair ranks p in [0,P), P = m(m+1)/2:
//      pairtab[p] = i | j<<8
//      coltab[c]  = p | k<<16  where column c = pps[p] * xsel[k]
//        [0,m)      order-1: p = P (sentinel pps=1), k = c
//        [m, m+P)   order-2: p = rank,               k = m (sentinel x=1)
//        [m+P, T)   order-3: run over k in [j, m) for each pair (i,j)
// ---------------------------------------------------------------------------
__global__ void maskde_setup(const void* __restrict__ mask_raw, int m,
                             int* __restrict__ idx_out,
                             uint32_t* __restrict__ pairtab,
                             uint32_t* __restrict__ coltab, int P) {
    int tid = blockIdx.x * blockDim.x + threadIdx.x;
    if (tid == 0) {
        const uint8_t* b8  = (const uint8_t*)mask_raw;
        const int*     b32 = (const int*)mask_raw;
        const float*   bf  = (const float*)mask_raw;
        int cnt = 0; bool ok = true;
        for (int i = 0; i < DMAX; ++i) { uint8_t v = b8[i]; if (v > 1) ok = false; cnt += (v != 0); }
        int mode;
        if (ok && cnt == m) {
            mode = 0;
        } else {
            cnt = 0; ok = true;
            for (int i = 0; i < DMAX; ++i) { int v = b32[i]; if (v != 0 && v != 1) ok = false; cnt += (v != 0); }
            mode = (ok && cnt == m) ? 1 : 2;
        }
        int k = 0;
        for (int i = 0; i < DMAX && k < m; ++i) {
            bool on = (mode == 0) ? (b8[i] != 0)
                    : (mode == 1) ? (b32[i] != 0)
                                  : (bf[i] != 0.0f);
            if (on) idx_out[k++] = i;
        }
    }

    int stride = gridDim.x * blockDim.x;
    for (int p = tid; p < P; p += stride) {
        int rem = p, i = 0;
        while (rem >= m - i) { rem -= (m - i); ++i; }
        int j = i + rem;

        pairtab[p] = (uint32_t)i | ((uint32_t)j << 8);

        if (p < m)
            coltab[p] = (uint32_t)P | ((uint32_t)p << 16);      // order-1
        coltab[m + p] = (uint32_t)p | ((uint32_t)m << 16);      // order-2

        // order-3 run for pair (i,j)
        int mi = m - i;
        long long Si  = ((long long)m * (m + 1) * (m + 2)
                       - (long long)mi * (mi + 1) * (mi + 2)) / 6;
        int Rij = ((m - i) + (m - j + 1)) * (j - i) / 2;
        uint32_t* t3 = coltab + m + P + Si + Rij;
        for (int k3 = j; k3 < m; ++k3)
            t3[k3 - j] = (uint32_t)p | ((uint32_t)k3 << 16);
    }
}

// ---------------------------------------------------------------------------
// Build shifted table copies: copy s (s=1..3) at coltab + s*tpad holds
// copy_s[q] = coltab[q + s], so a row whose float4 region starts at column
// s can load 16B-aligned uint4 table entries.  Padding -> safe sentinel.
// ---------------------------------------------------------------------------
__global__ void maskde_copies(uint32_t* __restrict__ coltab, int tpad, int T,
                              int m, int P) {
    int q = blockIdx.x * blockDim.x + threadIdx.x;
    int total = 3 * tpad;
    uint32_t sentinel = (uint32_t)P | ((uint32_t)m << 16);  // pps=1 * xls=1
    for (; q < total; q += gridDim.x * blockDim.x) {
        int s   = 1 + q / tpad;
        int off = q - (s - 1) * tpad;
        uint32_t v = (off + s < T) ? coltab[off + s] : sentinel;
        coltab[s * tpad + off] = v;
    }
}

// ---------------------------------------------------------------------------
// Main kernel: one block per row.
//   LDS: xls[m+1] (+1.0 sentinel), pps[P+1] pair products (+1.0 sentinel).
//   Each output element = pps[p] * xls[k]: 2 LDS reads + 1 mul.
//   Main loop: one aligned uint4 table load + one aligned float4 store.
// ---------------------------------------------------------------------------
__global__ __launch_bounds__(BLK) void
maskde_expand(const float* __restrict__ x, const int* __restrict__ idx,
              const uint32_t* __restrict__ pairtab,
              const uint32_t* __restrict__ coltab, int tpad,
              float* __restrict__ out, int m, int T, int P) {
    __shared__ float xls[DMAX + 1];
    extern __shared__ float pps[];   // P+1 floats

    const int row = blockIdx.x;
    const int tid = threadIdx.x;

    if (tid <= m)
        xls[tid] = (tid < m) ? x[row * DMAX + idx[tid]] : 1.0f;
    __syncthreads();

    for (int p = tid; p <= P; p += BLK) {
        float v = 1.0f;
        if (p < P) {
            uint32_t ij = pairtab[p];
            v = xls[ij & 0xFF] * xls[(ij >> 8) & 0xFF];
        }
        pps[p] = v;
    }
    __syncthreads();

    float* orow = out + (size_t)row * (size_t)T;
    uintptr_t a0 = (uintptr_t)orow;
    int k0 = (int)(((16 - (a0 & 15)) & 15) >> 2);
    if (k0 > T) k0 = T;

    // scalar prologue (base table copy)
    if (tid < k0) {
        uint32_t e = coltab[tid];
        orow[tid] = pps[e & 0xFFFF] * xls[e >> 16];
    }

    const int nv = (T - k0) >> 2;
    // shifted copy k0: entry q corresponds to column q + k0, 16B aligned
    const uint4* tbv = (const uint4*)(coltab + (size_t)k0 * (size_t)tpad);
    float* ovbase = orow + k0;

    for (int v = tid; v < nv; v += BLK) {
        uint4 e = tbv[v];
        f32x4 o;
        o.x = pps[e.x & 0xFFFF] * xls[e.x >> 16];
        o.y = pps[e.y & 0xFFFF] * xls[e.y >> 16];
        o.z = pps[e.z & 0xFFFF] * xls[e.z >> 16];
        o.w = pps[e.w & 0xFFFF] * xls[e.w >> 16];
        *(f32x4*)(ovbase + 4 * v) = o;
    }

    // scalar tail (base table copy)
    int c = k0 + 4 * nv + tid;
    if (c < T) {
        uint32_t e = coltab[c];
        orow[c] = pps[e & 0xFFFF] * xls[e >> 16];
    }
}

extern "C" void kernel_launch(void* const* d_in, const int* in_sizes, int n_in,
                              void* d_out, int out_size, void* d_ws, size_t ws_size,
                              hipStream_t stream) {
    const float* x    = (const float*)d_in[0];
    const void*  mask = d_in[1];
    float*       out  = (float*)d_out;

    int rows = in_sizes[0] / DMAX;
    if (rows <= 0 || out_size <= 0) return;
    long long T = (long long)out_size / rows;

    // recover m from T(m) = m + m(m+1)/2 + m(m+1)(m+2)/6
    int m = -1;
    for (int mm = 0; mm <= DMAX; ++mm) {
        long long t = (long long)mm
                    + (long long)mm * (mm + 1) / 2
                    + (long long)mm * (mm + 1) * (mm + 2) / 6;
        if (t == T) { m = mm; break; }
    }
    if (m <= 0) return;

    int P    = m * (m + 1) / 2;
    int tpad = (int)((T + 3) & ~3LL);        // entries per table copy (16B mult)

    int*      idx     = (int*)d_ws;                       // 512 B
    uint32_t* pairtab = (uint32_t*)((char*)d_ws + 1024);  // ≤13 KB
    uint32_t* coltab  = (uint32_t*)((char*)d_ws + 32768); // 4 copies × tpad

    int sblocks = (P + 255) / 256;
    if (sblocks < 1) sblocks = 1;
    maskde_setup<<<sblocks, 256, 0, stream>>>(mask, m, idx, pairtab, coltab, P);

    int cblocks = (3 * tpad + 255) / 256;
    maskde_copies<<<cblocks, 256, 0, stream>>>(coltab, tpad, (int)T, m, P);

    size_t shmem = (size_t)(P + 1) * sizeof(float);
    maskde_expand<<<rows, BLK, shmem, stream>>>(x, idx, pairtab, coltab, tpad,
                                                out, m, (int)T, P);
}